// Round 9
// baseline (122.334 us; speedup 1.0000x reference)
//
#include <hip/hip_runtime.h>
#include <math.h>

#define NUM_CLASSES 80
#define REG_MAX 16
#define NCH 144            // 4*REG_MAX + NUM_CLASSES
#define A_TOT 8400         // 80*80 + 40*40 + 20*20
#define BATCH 32
#define MAX_DET 300
#define CONF_THR 0.25f
#define IOU_THR 0.7f
#define MAX_WH 7680.0f
#define MASK_W 10          // ceil(300/32)
#define MROW 324           // mask row stride: 4-aligned (uint4) and %32 != 0
#define CHUNK 1050         // 8400 / 8 chunks per batch
#define NCHUNK 8
#define KPAD 1536          // 3 * 512

// ---------------------------------------------------------------------------
// K1: scores + argmax class (class channels only). 4 threads/anchor,
// coalesced float4 reads. Grid 4200 x 256. (unchanged)
// ---------------------------------------------------------------------------
__global__ __launch_bounds__(256) void score_kernel(
    const float* __restrict__ p3, const float* __restrict__ p4,
    const float* __restrict__ p5,
    float* __restrict__ scores, int* __restrict__ clsArr)
{
    const int t = blockIdx.x * 256 + threadIdx.x;
    const int g = t >> 2;                  // anchor id in [0, 268800)
    const int p = t & 3;
    const int b = g / A_TOT;
    const int a = g - b * A_TOT;

    const float* src;
    if (a < 6400)      src = p3 + ((size_t)b * 6400 + a) * NCH;
    else if (a < 8000) src = p4 + ((size_t)b * 1600 + (a - 6400)) * NCH;
    else               src = p5 + ((size_t)b * 400  + (a - 8000)) * NCH;

    const float4* s4 = (const float4*)src;
    float best = -INFINITY;
    int cbest = p * 4;
    #pragma unroll
    for (int q = 0; q < 5; ++q) {
        float4 c4 = s4[16 + q * 4 + p];    // coalesced: p spans one 64B line
        int c = q * 16 + p * 4;
        if (c4.x > best) { best = c4.x; cbest = c + 0; }
        if (c4.y > best) { best = c4.y; cbest = c + 1; }
        if (c4.z > best) { best = c4.z; cbest = c + 2; }
        if (c4.w > best) { best = c4.w; cbest = c + 3; }
    }
    #pragma unroll
    for (int d = 1; d < 4; d <<= 1) {
        float ob = __shfl_xor(best, d, 64);
        int   oc = __shfl_xor(cbest, d, 64);
        if (ob > best || (ob == best && oc < cbest)) { best = ob; cbest = oc; }
    }

    if (p == 0) {
        float sig = 1.0f / (1.0f + expf(-best));
        scores[g] = (sig > CONF_THR) ? sig : 0.0f;
        clsArr[g] = cbest;
    }
}

// ---------------------------------------------------------------------------
// K2 (R9): local exact top-300 per 1050-anchor chunk. 256 blocks x 512
// (8 blocks per batch) -> full-chip parallel selection.
// Rank-by-count with broadcast inner loop; writes descending 300-list.
// ---------------------------------------------------------------------------
__global__ __launch_bounds__(512) void localtop_kernel(
    const float* __restrict__ scores,
    unsigned long long* __restrict__ gloc)     // [BATCH][NCHUNK][MAX_DET]
{
    __shared__ unsigned long long keys[KPAD];
    __shared__ unsigned long long sortedLoc[MAX_DET];

    const int bid = blockIdx.x;
    const int b = bid >> 3;
    const int c = bid & 7;
    const int tid = threadIdx.x;
    const int base = c * CHUNK;                // batch-local anchor base
    const float* sc = scores + (size_t)b * A_TOT + base;

    // --- stage keys (0 for inactive / pad) ----------------------------------
    #pragma unroll
    for (int q = 0; q < 3; ++q) {
        int i = tid + q * 512;
        unsigned long long k = 0ULL;
        if (i < CHUNK) {
            float s = sc[i];
            if (s > 0.0f) {
                unsigned sb = __float_as_uint(s);
                unsigned gi = (unsigned)(base + i);
                k = ((unsigned long long)sb << 32) |
                    (unsigned long long)(0xFFFFFFFFu - gi);
            }
        }
        keys[i] = k;
    }
    if (tid < MAX_DET) sortedLoc[tid] = 0ULL;
    __syncthreads();

    // --- rank-by-count: 3 keys per thread, broadcast reads ------------------
    unsigned long long mk0 = keys[tid];
    unsigned long long mk1 = keys[tid + 512];
    unsigned long long mk2 = keys[tid + 1024];
    int r0 = 0, r1 = 0, r2 = 0;
    #pragma unroll 4
    for (int j = 0; j < CHUNK; ++j) {
        unsigned long long kj = keys[j];       // uniform addr -> broadcast
        r0 += (kj > mk0) ? 1 : 0;
        r1 += (kj > mk1) ? 1 : 0;
        r2 += (kj > mk2) ? 1 : 0;
    }
    if (mk0 != 0ULL && r0 < MAX_DET) sortedLoc[r0] = mk0;
    if (mk1 != 0ULL && r1 < MAX_DET) sortedLoc[r1] = mk1;
    if (mk2 != 0ULL && r2 < MAX_DET) sortedLoc[r2] = mk2;
    __syncthreads();

    unsigned long long* dst = gloc + ((size_t)b * NCHUNK + c) * MAX_DET;
    if (tid < MAX_DET) dst[tid] = sortedLoc[tid];
}

// ---------------------------------------------------------------------------
// K3 (R9): per-batch merge (binary-search global rank over 8 sorted lists)
// + DFL decode of survivors + IoU mask + greedy scan + write. 32 x 1024.
// ---------------------------------------------------------------------------
__global__ __launch_bounds__(1024, 4) void nms_merge_kernel(
    const float* __restrict__ p3, const float* __restrict__ p4,
    const float* __restrict__ p5,
    const int* __restrict__ clsArr,
    const unsigned long long* __restrict__ gloc,
    float* __restrict__ out)
{
    __shared__ unsigned long long lists[NCHUNK][MAX_DET];
    __shared__ unsigned long long sortedK[MAX_DET];
    __shared__ float4 cbox4[MAX_DET];
    __shared__ float4 obox4[MAX_DET];
    __shared__ float oarea[MAX_DET];
    __shared__ float tops[MAX_DET];
    __shared__ float tcls[MAX_DET];
    __shared__ unsigned mask[MASK_W][MROW];
    __shared__ unsigned aliveW[MASK_W];
    __shared__ unsigned keepW[MASK_W];

    const int b = blockIdx.x;
    const int tid = threadIdx.x;
    const int lane = tid & 63;
    const int* cl = clsArr + (size_t)b * A_TOT;
    const unsigned long long* gl = gloc + (size_t)b * NCHUNK * MAX_DET;

    // --- load 8 sorted lists + zero sortedK ---------------------------------
    for (int i = tid; i < NCHUNK * MAX_DET; i += 1024)
        ((unsigned long long*)lists)[i] = gl[i];
    if (tid < MAX_DET) sortedK[tid] = 0ULL;
    __syncthreads();

    // --- global rank: own position + binary-search counts in other lists ----
    for (int s = tid; s < NCHUNK * MAX_DET; s += 1024) {
        int c = s / MAX_DET;
        int r = s - c * MAX_DET;
        unsigned long long k = lists[c][r];
        if (k != 0ULL) {
            int rank = r;
            #pragma unroll
            for (int c2 = 0; c2 < NCHUNK; ++c2) {
                if (c2 != c) {
                    int lo = 0, hi = MAX_DET;
                    while (lo < hi) {
                        int mid = (lo + hi) >> 1;
                        if (lists[c2][mid] > k) lo = mid + 1; else hi = mid;
                    }
                    rank += lo;
                }
            }
            if (rank < MAX_DET) sortedK[rank] = k;
        }
    }
    __syncthreads();

    // --- DFL box decode for survivors (4 threads/anchor, 2 sweeps) ----------
    const int gbase = lane & ~3;
    #pragma unroll
    for (int sweep = 0; sweep < 2; ++sweep) {
        int det = sweep * 256 + (tid >> 2);
        int p = tid & 3;
        unsigned long long key = (det < MAX_DET) ? sortedK[det] : 0ULL;
        float distp = 0.0f;
        unsigned i = 0xFFFFFFFFu - (unsigned)(key & 0xFFFFFFFFull);

        if (key != 0ULL) {
            const float* rowp;
            if (i < 6400)      rowp = p3 + ((size_t)b * 6400 + i) * NCH;
            else if (i < 8000) rowp = p4 + ((size_t)b * 1600 + (i - 6400)) * NCH;
            else               rowp = p5 + ((size_t)b * 400  + (i - 8000)) * NCH;
            const float4* s4 = (const float4*)rowp;
            float vv[16];
            float4 r0 = s4[p * 4 + 0];
            float4 r1 = s4[p * 4 + 1];
            float4 r2 = s4[p * 4 + 2];
            float4 r3 = s4[p * 4 + 3];
            vv[0]=r0.x; vv[1]=r0.y; vv[2]=r0.z; vv[3]=r0.w;
            vv[4]=r1.x; vv[5]=r1.y; vv[6]=r1.z; vv[7]=r1.w;
            vv[8]=r2.x; vv[9]=r2.y; vv[10]=r2.z; vv[11]=r2.w;
            vv[12]=r3.x; vv[13]=r3.y; vv[14]=r3.z; vv[15]=r3.w;
            float m = vv[0];
            #pragma unroll
            for (int k2 = 1; k2 < 16; ++k2) m = fmaxf(m, vv[k2]);
            float ssum = 0.0f, wsum = 0.0f;
            #pragma unroll
            for (int k2 = 0; k2 < 16; ++k2) {
                float e = expf(vv[k2] - m);
                ssum += e;
                wsum += e * (float)k2;
            }
            distp = wsum / ssum;
        }
        float d0 = __shfl(distp, gbase + 0, 64);
        float d1 = __shfl(distp, gbase + 1, 64);
        float d2 = __shfl(distp, gbase + 2, 64);
        float d3 = __shfl(distp, gbase + 3, 64);

        if (det < MAX_DET && p == 0) {
            float s = __uint_as_float((unsigned)(key >> 32));
            tops[det] = s;
            float4 bb = make_float4(0.f, 0.f, 0.f, 0.f);
            float4 ob = bb;
            float cf = 0.0f;
            if (key != 0ULL) {
                int gyi, gxi; float strd;
                if (i < 6400)      { gyi = i / 80; gxi = i - gyi * 80; strd = 8.0f; }
                else if (i < 8000) { int li = i - 6400; gyi = li / 40; gxi = li - gyi * 40; strd = 16.0f; }
                else               { int li = i - 8000; gyi = li / 20; gxi = li - gyi * 20; strd = 32.0f; }
                float gx = (float)gxi + 0.5f;
                float gy = (float)gyi + 0.5f;
                float x1 = gx - d0, y1 = gy - d1;
                float x2 = gx + d2, y2 = gy + d3;
                float cx = ((x1 + x2) * 0.5f) * strd;
                float cy = ((y1 + y2) * 0.5f) * strd;
                float bw = (x2 - x1) * strd;
                float bh = (y2 - y1) * strd;
                float hx = bw * 0.5f, hy = bh * 0.5f;
                bb = make_float4(cx - hx, cy - hy, cx + hx, cy + hy);
                cf = (float)cl[i];
                float off = cf * MAX_WH;
                ob = make_float4(bb.x + off, bb.y + off, bb.z + off, bb.w + off);
            }
            cbox4[det] = bb;
            obox4[det] = ob;
            tcls[det] = cf;
            oarea[det] = (ob.z - ob.x) * (ob.w - ob.y);
        }
    }
    __syncthreads();

    // --- 300x300 IoU > thr bitmask ------------------------------------------
    for (int task = tid; task < MASK_W * MAX_DET; task += 1024) {
        int w = task / MAX_DET;
        int i = task - w * MAX_DET;
        float4 a = obox4[i];
        float aa = oarea[i];
        unsigned bits = 0;
        int j0 = w * 32;
        int jend = min(32, MAX_DET - j0);
        for (int jj = 0; jj < jend; ++jj) {
            int j = j0 + jj;
            float4 bo = obox4[j];
            float ab = oarea[j];
            float lx = fmaxf(a.x, bo.x), ly = fmaxf(a.y, bo.y);
            float rx = fminf(a.z, bo.z), ry = fminf(a.w, bo.w);
            float iw = fmaxf(rx - lx, 0.0f), ih = fmaxf(ry - ly, 0.0f);
            float inter = iw * ih;
            float iou = inter / (aa + ab - inter + 1e-7f);
            if (iou > IOU_THR) bits |= (1u << jj);
        }
        mask[w][i] = bits;
    }
    if (tid < MASK_W) {
        unsigned a = 0u;
        #pragma unroll
        for (int ii = 0; ii < 32; ++ii) {
            int i = tid * 32 + ii;
            if (i < MAX_DET && tops[i] > 0.0f) a |= (1u << ii);
        }
        aliveW[tid] = a;
    }
    __syncthreads();

    // --- greedy scan: per-word broadcast into static regs, VALU-only chain ---
    if (tid < 64) {
        unsigned supp = 0u;                // lane w'<10: suppressed word w'
        for (int w = 0; w < MASK_W; ++w) {
            unsigned suppcur = __shfl(supp, w, 64);
            unsigned aw = aliveW[w];
            unsigned m[32];
            #pragma unroll
            for (int q = 0; q < 8; ++q) {  // uniform addr -> LDS broadcast
                uint4 mq = *(const uint4*)&mask[w][w * 32 + q * 4];
                m[q*4+0] = mq.x; m[q*4+1] = mq.y;
                m[q*4+2] = mq.z; m[q*4+3] = mq.w;
            }
            unsigned kw = 0u;
            #pragma unroll
            for (int ii = 0; ii < 32; ++ii) {
                if (w * 32 + ii < MAX_DET) {
                    bool live = ((aw >> ii) & 1u) && !((suppcur >> ii) & 1u);
                    if (live) { suppcur |= m[ii]; kw |= (1u << ii); }
                }
            }
            if (tid == 0) keepW[w] = kw;
            if (tid < MASK_W) {            // off critical chain
                unsigned acc = 0u;
                #pragma unroll
                for (int ii = 0; ii < 32; ++ii) {
                    if ((kw >> ii) & 1u) acc |= mask[tid][w * 32 + ii];
                }
                supp |= acc;
            }
        }
    }
    __syncthreads();

    // --- write output [cbox(4), score, cls], zero if not kept ---------------
    float* ob = out + (size_t)b * MAX_DET * 6;
    for (int e = tid; e < MAX_DET * 6; e += 1024) {
        int i = e / 6, c = e - (e / 6) * 6;
        float val = 0.0f;
        if ((keepW[i >> 5] >> (i & 31)) & 1u) {
            if (c < 4)        val = (&cbox4[i].x)[c];
            else if (c == 4)  val = tops[i];
            else              val = tcls[i];
        }
        ob[e] = val;
    }
}

// ---------------------------------------------------------------------------
extern "C" void kernel_launch(void* const* d_in, const int* in_sizes, int n_in,
                              void* d_out, int out_size, void* d_ws, size_t ws_size,
                              hipStream_t stream) {
    const float* p3 = (const float*)d_in[0];
    const float* p4 = (const float*)d_in[1];
    const float* p5 = (const float*)d_in[2];
    float* out = (float*)d_out;

    char* base = (char*)d_ws;
    float*              scores = (float*)base;                      // 268800 f32
    int*                cls    = (int*)(base + 1075200);            // 268800 i32
    unsigned long long* gloc   = (unsigned long long*)(base + 2150400); // 32*8*300 u64

    score_kernel<<<4200, 256, 0, stream>>>(p3, p4, p5, scores, cls);
    localtop_kernel<<<BATCH * NCHUNK, 512, 0, stream>>>(scores, gloc);
    nms_merge_kernel<<<BATCH, 1024, 0, stream>>>(p3, p4, p5, cls, gloc, out);
}

// Round 10
// 66.850 us; speedup vs baseline: 1.8300x; 1.8300x over previous
//
#include <hip/hip_runtime.h>
#include <math.h>

#define NUM_CLASSES 80
#define REG_MAX 16
#define NCH 144            // 4*REG_MAX + NUM_CLASSES
#define A_TOT 8400         // 80*80 + 40*40 + 20*20
#define BATCH 32
#define MAX_DET 300
#define DET_PAD 320        // padded survivor count (zero boxes 300..319)
#define CONF_THR 0.25f
#define IOU_THR 0.7f
#define MAX_WH 7680.0f
#define CAP 1024
#define NBINS 1024
#define MASK_W 10          // ceil(300/32)
#define MROW 324           // mask row stride: 4-aligned (uint4) and %32 != 0
#define NTRI 1760          // sum_w (w+1)*32 = triangle task count

// ---------------------------------------------------------------------------
// K1: scores + argmax class (class channels only). 4 threads/anchor,
// coalesced float4 reads. Grid 4200 x 256. (unchanged)
// ---------------------------------------------------------------------------
__global__ __launch_bounds__(256) void score_kernel(
    const float* __restrict__ p3, const float* __restrict__ p4,
    const float* __restrict__ p5,
    float* __restrict__ scores, int* __restrict__ clsArr)
{
    const int t = blockIdx.x * 256 + threadIdx.x;
    const int g = t >> 2;                  // anchor id in [0, 268800)
    const int p = t & 3;
    const int b = g / A_TOT;
    const int a = g - b * A_TOT;

    const float* src;
    if (a < 6400)      src = p3 + ((size_t)b * 6400 + a) * NCH;
    else if (a < 8000) src = p4 + ((size_t)b * 1600 + (a - 6400)) * NCH;
    else               src = p5 + ((size_t)b * 400  + (a - 8000)) * NCH;

    const float4* s4 = (const float4*)src;
    float best = -INFINITY;
    int cbest = p * 4;
    #pragma unroll
    for (int q = 0; q < 5; ++q) {
        float4 c4 = s4[16 + q * 4 + p];    // coalesced: p spans one 64B line
        int c = q * 16 + p * 4;
        if (c4.x > best) { best = c4.x; cbest = c + 0; }
        if (c4.y > best) { best = c4.y; cbest = c + 1; }
        if (c4.z > best) { best = c4.z; cbest = c + 2; }
        if (c4.w > best) { best = c4.w; cbest = c + 3; }
    }
    #pragma unroll
    for (int d = 1; d < 4; d <<= 1) {
        float ob = __shfl_xor(best, d, 64);
        int   oc = __shfl_xor(cbest, d, 64);
        if (ob > best || (ob == best && oc < cbest)) { best = ob; cbest = oc; }
    }

    if (p == 0) {
        float sig = 1.0f / (1.0f + expf(-best));
        scores[g] = (sig > CONF_THR) ? sig : 0.0f;
        clsArr[g] = cbest;
    }
}

// ---------------------------------------------------------------------------
// K2 (R10): FUSED select + nms. 32 blocks x 1024, one block per batch.
// = R8 kernel with Phase E rewritten: triangle-only tasks, fixed 32-iter
// inner loop, 8-wide unroll (batched LDS reads).
// ---------------------------------------------------------------------------
__global__ __launch_bounds__(1024, 4) void nms_fused_kernel(
    const float* __restrict__ p3, const float* __restrict__ p4,
    const float* __restrict__ p5,
    const float* __restrict__ scores, const int* __restrict__ clsArr,
    float* __restrict__ out)
{
    __shared__ float sc_l[A_TOT];
    __shared__ unsigned hist[NBINS];
    __shared__ unsigned wtot[16];
    __shared__ unsigned woff[16];
    __shared__ unsigned long long cand[CAP];
    __shared__ unsigned long long sortedK[MAX_DET];
    __shared__ float4 cbox4[MAX_DET];
    __shared__ float4 obox4[DET_PAD];
    __shared__ float oarea[DET_PAD];
    __shared__ float tops[MAX_DET];
    __shared__ float tcls[MAX_DET];
    __shared__ unsigned mask[MASK_W][MROW];
    __shared__ unsigned aliveW[MASK_W];
    __shared__ unsigned keepW[MASK_W];
    __shared__ int bstar;
    __shared__ unsigned cnt;

    const int b = blockIdx.x;
    const int tid = threadIdx.x;
    const int lane = tid & 63;
    const int wv = tid >> 6;
    const float* sc = scores + (size_t)b * A_TOT;
    const int* cl = clsArr + (size_t)b * A_TOT;

    hist[tid] = 0;
    if (tid < MAX_DET) sortedK[tid] = 0ULL;
    if (tid == 0) { cnt = 0u; bstar = 0; }
    __syncthreads();

    // --- Phase A: stage scores to LDS + histogram of nonzero -----------------
    #pragma unroll
    for (int k = 0; k < 9; ++k) {
        int i = tid + k * 1024;
        if (i < A_TOT) {
            float s = sc[i];
            sc_l[i] = s;
            if (s > 0.0f) {
                int bin = min((int)(s * (float)NBINS), NBINS - 1);
                atomicAdd(&hist[bin], 1u);
            }
        }
    }
    __syncthreads();

    // --- suffix scan (wave shuffle + 16 wave totals) -------------------------
    unsigned v = hist[tid];
    #pragma unroll
    for (int d = 1; d < 64; d <<= 1) {
        unsigned o = __shfl_down(v, d, 64);
        if (lane + d < 64) v += o;
    }
    if (lane == 0) wtot[wv] = v;
    __syncthreads();
    if (tid < 16) {
        unsigned u = wtot[tid];
        unsigned t2 = u;
        #pragma unroll
        for (int d = 1; d < 16; d <<= 1) {
            unsigned o = __shfl_down(t2, d, 64);
            if (tid + d < 16) t2 += o;
        }
        woff[tid] = t2 - u;
    }
    __syncthreads();
    unsigned suff = v + woff[wv];
    hist[tid] = suff;
    __syncthreads();

    if (hist[tid] >= MAX_DET && (tid == NBINS - 1 || hist[tid + 1] < MAX_DET))
        bstar = tid;
    __syncthreads();
    const int bs = bstar;

    // --- Phase B: ballot compact (one LDS atomic per wave per slice) ---------
    #pragma unroll
    for (int k = 0; k < 9; ++k) {
        int i = tid + k * 1024;
        float s = (i < A_TOT) ? sc_l[i] : 0.0f;
        bool pass = false;
        if (s > 0.0f) {
            int bin = min((int)(s * (float)NBINS), NBINS - 1);
            pass = (bin >= bs);
        }
        unsigned long long mb = __ballot(pass);
        unsigned nw = (unsigned)__popcll(mb);
        unsigned base = 0u;
        if (lane == 0) base = nw ? atomicAdd(&cnt, nw) : 0u;
        base = __shfl(base, 0, 64);
        if (pass) {
            unsigned off = (unsigned)__popcll(mb & ((1ULL << lane) - 1ULL));
            unsigned pos = base + off;
            if (pos < CAP) {
                unsigned sb = __float_as_uint(s);
                cand[pos] = ((unsigned long long)sb << 32) |
                            (unsigned long long)(0xFFFFFFFFu - (unsigned)i);
            }
        }
    }
    __syncthreads();

    // --- Phase C: rank-by-count (keys unique -> exact top_k order) -----------
    const int n = min((int)cnt, CAP);
    if (tid < n) {
        unsigned long long mykey = cand[tid];
        int r = 0;
        #pragma unroll 8
        for (int j = 0; j < n; ++j) r += (cand[j] > mykey) ? 1 : 0;
        if (r < MAX_DET) sortedK[r] = mykey;
    }
    __syncthreads();

    // --- Phase D: DFL box decode for survivors (4 threads/anchor, 2 sweeps) --
    const int gbase = lane & ~3;
    #pragma unroll
    for (int sweep = 0; sweep < 2; ++sweep) {
        int det = sweep * 256 + (tid >> 2);
        int p = tid & 3;
        unsigned long long key = (det < MAX_DET) ? sortedK[det] : 0ULL;
        float distp = 0.0f;
        unsigned i = 0xFFFFFFFFu - (unsigned)(key & 0xFFFFFFFFull);

        if (key != 0ULL) {
            const float* rowp;
            if (i < 6400)      rowp = p3 + ((size_t)b * 6400 + i) * NCH;
            else if (i < 8000) rowp = p4 + ((size_t)b * 1600 + (i - 6400)) * NCH;
            else               rowp = p5 + ((size_t)b * 400  + (i - 8000)) * NCH;
            const float4* s4 = (const float4*)rowp;
            float vv[16];
            float4 r0 = s4[p * 4 + 0];
            float4 r1 = s4[p * 4 + 1];
            float4 r2 = s4[p * 4 + 2];
            float4 r3 = s4[p * 4 + 3];
            vv[0]=r0.x; vv[1]=r0.y; vv[2]=r0.z; vv[3]=r0.w;
            vv[4]=r1.x; vv[5]=r1.y; vv[6]=r1.z; vv[7]=r1.w;
            vv[8]=r2.x; vv[9]=r2.y; vv[10]=r2.z; vv[11]=r2.w;
            vv[12]=r3.x; vv[13]=r3.y; vv[14]=r3.z; vv[15]=r3.w;
            float m = vv[0];
            #pragma unroll
            for (int k2 = 1; k2 < 16; ++k2) m = fmaxf(m, vv[k2]);
            float ssum = 0.0f, wsum = 0.0f;
            #pragma unroll
            for (int k2 = 0; k2 < 16; ++k2) {
                float e = expf(vv[k2] - m);
                ssum += e;
                wsum += e * (float)k2;
            }
            distp = wsum / ssum;
        }
        float d0 = __shfl(distp, gbase + 0, 64);
        float d1 = __shfl(distp, gbase + 1, 64);
        float d2 = __shfl(distp, gbase + 2, 64);
        float d3 = __shfl(distp, gbase + 3, 64);

        if (det < MAX_DET && p == 0) {
            float s = __uint_as_float((unsigned)(key >> 32));
            tops[det] = s;
            float4 bb = make_float4(0.f, 0.f, 0.f, 0.f);
            float4 ob = bb;
            float cf = 0.0f;
            if (key != 0ULL) {
                int gyi, gxi; float strd;
                if (i < 6400)      { gyi = i / 80; gxi = i - gyi * 80; strd = 8.0f; }
                else if (i < 8000) { int li = i - 6400; gyi = li / 40; gxi = li - gyi * 40; strd = 16.0f; }
                else               { int li = i - 8000; gyi = li / 20; gxi = li - gyi * 20; strd = 32.0f; }
                float gx = (float)gxi + 0.5f;
                float gy = (float)gyi + 0.5f;
                float x1 = gx - d0, y1 = gy - d1;
                float x2 = gx + d2, y2 = gy + d3;
                float cx = ((x1 + x2) * 0.5f) * strd;
                float cy = ((y1 + y2) * 0.5f) * strd;
                float bw = (x2 - x1) * strd;
                float bh = (y2 - y1) * strd;
                float hx = bw * 0.5f, hy = bh * 0.5f;
                bb = make_float4(cx - hx, cy - hy, cx + hx, cy + hy);
                cf = (float)cl[i];
                float off = cf * MAX_WH;
                ob = make_float4(bb.x + off, bb.y + off, bb.z + off, bb.w + off);
            }
            cbox4[det] = bb;
            obox4[det] = ob;
            tcls[det] = cf;
            oarea[det] = (ob.z - ob.x) * (ob.w - ob.y);
        } else if (det >= MAX_DET && det < DET_PAD && p == 0) {
            // zero-pad 300..319 so Phase E's inner loop is a fixed 32 iters
            obox4[det] = make_float4(0.f, 0.f, 0.f, 0.f);
            oarea[det] = 0.0f;
        }
    }
    __syncthreads();

    // --- Phase E: IoU > thr bitmask, TRIANGLE tasks only ---------------------
    // task t -> (w, i) with i < (w+1)*32 (row i needs word w iff some j>i in
    // word w; within-word earlier-j bits are consumed only after set -> safe).
    // off(w) = 16*w*(w+1); NTRI = 1760 tasks over 1024 threads.
    for (int t = tid; t < NTRI; t += 1024) {
        int w = (int)((sqrtf(16.0f + 4.0f * (float)t) - 4.0f) * 0.125f);
        while (16 * (w + 1) * (w + 2) <= t) ++w;
        while (16 * w * (w + 1) > t) --w;
        int i = t - 16 * w * (w + 1);          // i in [0, (w+1)*32)
        const int j0 = w * 32;

        float4 a = obox4[i];
        float aa = oarea[i];
        unsigned bits = 0;
        #pragma unroll 8
        for (int jj = 0; jj < 32; ++jj) {
            int j = j0 + jj;
            float4 bo = obox4[j];
            float ab = oarea[j];
            float lx = fmaxf(a.x, bo.x), ly = fmaxf(a.y, bo.y);
            float rx = fminf(a.z, bo.z), ry = fminf(a.w, bo.w);
            float iw = fmaxf(rx - lx, 0.0f), ih = fmaxf(ry - ly, 0.0f);
            float inter = iw * ih;
            float iou = inter / (aa + ab - inter + 1e-7f);
            if (iou > IOU_THR) bits |= (1u << jj);
        }
        mask[w][i] = bits;
    }
    if (tid < MASK_W) {
        unsigned a = 0u;
        #pragma unroll
        for (int ii = 0; ii < 32; ++ii) {
            int i = tid * 32 + ii;
            if (i < MAX_DET && tops[i] > 0.0f) a |= (1u << ii);
        }
        aliveW[tid] = a;
    }
    __syncthreads();

    // --- Phase F: greedy scan (wave 0), word-pipelined -----------------------
    if (tid < 64) {
        unsigned supp = 0u;                // lane w'<10: suppressed word w'
        for (int w = 0; w < MASK_W; ++w) {
            unsigned suppcur = __shfl(supp, w, 64);
            unsigned aw = aliveW[w];
            unsigned m[32];
            #pragma unroll
            for (int q = 0; q < 8; ++q) {  // uniform addr -> LDS broadcast
                uint4 mq = *(const uint4*)&mask[w][w * 32 + q * 4];
                m[q*4+0] = mq.x; m[q*4+1] = mq.y;
                m[q*4+2] = mq.z; m[q*4+3] = mq.w;
            }
            unsigned kw = 0u;
            #pragma unroll
            for (int ii = 0; ii < 32; ++ii) {
                if (w * 32 + ii < MAX_DET) {
                    bool live = ((aw >> ii) & 1u) && !((suppcur >> ii) & 1u);
                    if (live) { suppcur |= m[ii]; kw |= (1u << ii); }
                }
            }
            if (tid == 0) keepW[w] = kw;
            if (tid < MASK_W) {            // merge into lane words (j>row only
                unsigned acc = 0u;         //  matters; stale words already read)
                #pragma unroll
                for (int ii = 0; ii < 32; ++ii) {
                    if ((kw >> ii) & 1u) acc |= mask[tid][w * 32 + ii];
                }
                supp |= acc;
            }
        }
    }
    __syncthreads();

    // --- Phase G: write output [cbox(4), score, cls], zero if not kept -------
    float* ob = out + (size_t)b * MAX_DET * 6;
    for (int e = tid; e < MAX_DET * 6; e += 1024) {
        int i = e / 6, c = e - (e / 6) * 6;
        float val = 0.0f;
        if ((keepW[i >> 5] >> (i & 31)) & 1u) {
            if (c < 4)        val = (&cbox4[i].x)[c];
            else if (c == 4)  val = tops[i];
            else              val = tcls[i];
        }
        ob[e] = val;
    }
}

// ---------------------------------------------------------------------------
extern "C" void kernel_launch(void* const* d_in, const int* in_sizes, int n_in,
                              void* d_out, int out_size, void* d_ws, size_t ws_size,
                              hipStream_t stream) {
    const float* p3 = (const float*)d_in[0];
    const float* p4 = (const float*)d_in[1];
    const float* p5 = (const float*)d_in[2];
    float* out = (float*)d_out;

    char* base = (char*)d_ws;
    float* scores = (float*)base;                     // 268800 f32
    int*   cls    = (int*)(base + 1075200);           // 268800 i32

    score_kernel<<<4200, 256, 0, stream>>>(p3, p4, p5, scores, cls);
    nms_fused_kernel<<<BATCH, 1024, 0, stream>>>(p3, p4, p5, scores, cls, out);
}